// Round 2
// baseline (320.195 us; speedup 1.0000x reference)
//
#include <hip/hip_runtime.h>
#include <stdint.h>

#define N_IMG 32
#define C_IN 256
#define K_OUT 256
#define HW 56
#define HP 58
#define SPATIAL (N_IMG*HW*HW)          /* 100352 */
#define KDIM (C_IN*9)                  /* 2304 */
#define XPAD_ELEMS (N_IMG*HP*HP*C_IN)  /* 27557888 */
#define XPAD_BYTES (XPAD_ELEMS*2)      /* 55115776 */
#define WT_BYTES (K_OUT*KDIM*2)        /* 1179648 */
#define OUT_ELEMS (N_IMG*K_OUT*HW*HW)  /* 25690112 */

/* GEMM pipeline geometry: BM=256, BN=128, BK=32, 3-buffer rotation */
#define NT 72                          /* 2304/32 K-tiles */
#define TILE_LDS 24576                 /* A 16 KB + B 8 KB */
#define LDS_TOT 73728                  /* 3 buffers -> 2 blocks/CU */

/* prep grid partition */
#define PREP_X_BLOCKS (SPATIAL/64)          /* 1568 */
#define PREP_Z_BLOCKS ((N_IMG*228*32)/256)  /* 912 */
#define PREP_W_BLOCKS K_OUT                 /* 256 */
#define PREP_BLOCKS (PREP_X_BLOCKS+PREP_Z_BLOCKS+PREP_W_BLOCKS)

typedef __bf16 bf16x8 __attribute__((ext_vector_type(8)));
typedef float  f32x4  __attribute__((ext_vector_type(4)));

static __device__ __forceinline__ unsigned short f2bf(float f) {
    unsigned u = __float_as_uint(f);
    u += 0x7fff + ((u >> 16) & 1);   // RNE
    return (unsigned short)(u >> 16);
}

static __device__ __forceinline__ void gld16(const void* g, void* l) {
    __builtin_amdgcn_global_load_lds(
        (const __attribute__((address_space(1))) void*)g,
        (__attribute__((address_space(3))) void*)l, 16, 0, 0);
}

// ---------------- fused prep: x->NHWC bf16 padded, border zero, W transform ----
__global__ __launch_bounds__(256) void prep(
    const float* __restrict__ x, const float* __restrict__ W,
    unsigned short* __restrict__ xpad, unsigned short* __restrict__ Wt) {
    const int b = blockIdx.x, t = threadIdx.x;
    if (b < PREP_X_BLOCKS) {
        __shared__ __align__(16) unsigned short lds[64 * 256];   // 32 KB
        const int n = b / 49, hw0 = (b % 49) * 64;
        const int l = t & 63, w0 = t >> 6;
        const float* xbase = x + (size_t)(n * C_IN) * 3136 + hw0 + l;
        #pragma unroll
        for (int i = 0; i < 16; ++i) {
            const int c4 = w0 * 64 + i * 4;      // 4 consecutive channels
            unsigned short v[4];
            #pragma unroll
            for (int j = 0; j < 4; ++j)
                v[j] = f2bf(xbase[(c4 + j) * 3136]);
            const int m = c4 >> 3, h8 = (c4 >> 2) & 1;   // wave-uniform
            *(uint2*)&lds[l * 256 + ((m ^ (l & 31)) << 3) + h8 * 4] = *(const uint2*)v;
        }
        __syncthreads();
        const int q = t & 31;
        #pragma unroll
        for (int j = 0; j < 8; ++j) {
            const int p = (t >> 5) + j * 8;
            const int hw = hw0 + p, h = hw / 56, w = hw - h * 56;
            uint4 v = *(const uint4*)&lds[p * 256 + ((q ^ (p & 31)) << 3)];
            *(uint4*)&xpad[((n * HP + h + 1) * HP + (w + 1)) * C_IN + q * 8] = v;
        }
    } else if (b < PREP_X_BLOCKS + PREP_Z_BLOCKS) {
        // ---- zero the pad border (one uint4 per thread) ----
        int idx = (b - PREP_X_BLOCKS) * 256 + t;
        int cell = idx >> 5, qq = idx & 31;
        int n = cell / 228, r = cell - n * 228;
        int h, w;
        if (r < 58)       { h = 0;            w = r; }
        else if (r < 116) { h = 57;           w = r - 58; }
        else if (r < 172) { h = r - 116 + 1;  w = 0; }
        else              { h = r - 172 + 1;  w = 57; }
        uint4 z = make_uint4(0u, 0u, 0u, 0u);
        *(uint4*)&xpad[((n * HP + h) * HP + w) * C_IN + qq * 8] = z;
    } else {
        // ---- W fp32 OIHW -> bf16 [k][rs][c] ----
        const int k = b - PREP_X_BLOCKS - PREP_Z_BLOCKS, c = t;
        const float* wp = W + (k * C_IN + c) * 9;
        #pragma unroll
        for (int rs = 0; rs < 9; ++rs)
            Wt[k * KDIM + rs * C_IN + c] = f2bf(wp[rs]);
    }
}

// ---------------- main: implicit GEMM, counted-vmcnt 3-buffer pipeline --------
// BM=256 (all out-ch) x BN=128 spatial, BK=32, 4 waves (2M x 2N), per-wave
// 128m x 64n = acc[8][4]. Tile t in buf[t%3]; tile t+2 staged during tile t
// (its buffer's previous occupant t-1 was consumed before the barrier that
// opened tile t). End-of-tile wait: vmcnt(6) while prefetching (t+1 resident,
// t+2 in flight); vmcnt(0) once prefetch stops (tail tiles MUST drain --
// vmcnt(6) with only 6 outstanding is a no-op => round-1's stale-tile race).
// setprio around MFMA clusters (T5).
// LDS chunk swizzle (rows 64 B, 4 chunks): phys = logical ^ ((row>>1)&3)
// -> 2-way bank aliasing on ds_read_b128 (free per m136). Staging applies the
// same involution on the per-lane GLOBAL source (linear LDS dest, rule 21).
__global__ __launch_bounds__(256, 2) void conv_gemm(
    const unsigned short* __restrict__ xpad,
    const unsigned short* __restrict__ Wt,
    float* __restrict__ out) {
    __shared__ __align__(16) char smem[LDS_TOT];
    const int t0 = threadIdx.x;
    const int w0 = t0 >> 6, l = t0 & 63;
    const int bx = blockIdx.x;
    const int p0 = ((bx & 7) * 98 + (bx >> 3)) * 128;  // XCD-swizzled tile base
    const int lm = l & 15, lq = l >> 4;
    const int wm = w0 >> 1, wn = w0 & 1;

    // ---- staging: per issue 16 rows x 4 chunks; lane l -> row +(l>>2),
    // phys chunk (l&3); fetches logical chunk (l&3)^((l>>3)&3) ----
    const int lr = l >> 2;
    const int lcS = (l & 3) ^ ((l >> 3) & 3);
    const int aSrc0 = (w0 * 16 + lr) * KDIM + lcS * 8;   // + j*64*KDIM + k0
    int bSrc[2];
    #pragma unroll
    for (int j = 0; j < 2; ++j) {
        int p = p0 + j * 64 + w0 * 16 + lr;
        int n = p / 3136; int rem = p - n * 3136;
        int h = rem / 56; int ww = rem - h * 56;
        bSrc[j] = ((n * HP + h) * HP + ww) * C_IN + lcS * 8;  // r=s=0 base
    }
    const int dstA = w0 * 1024;          // + j*4096 within A region
    const int dstB = 16384 + w0 * 1024;  // + j*4096 within B region

    // ---- fragment LDS offsets: row bits1-2 == lm bits1-2 for all frags ----
    const int chByte = ((lq ^ ((lm >> 1) & 3)) << 4);
    const int aOff0 = (wm * 128 + lm) * 64 + chByte;          // + ti*1024
    const int bOff0 = 16384 + (wn * 64 + lm) * 64 + chByte;   // + tj*1024

    f32x4 acc[8][4] = {};

    // ---- prologue: stage tiles 0,1 (12 loads/thread) ----
    #pragma unroll
    for (int tt = 0; tt < 2; ++tt) {
        const int base = tt * TILE_LDS;
        #pragma unroll
        for (int j = 0; j < 4; ++j)
            gld16(Wt + aSrc0 + j * (64 * KDIM) + tt * 32, smem + base + dstA + j * 4096);
        #pragma unroll
        for (int j = 0; j < 2; ++j)
            gld16(xpad + bSrc[j] + tt * 32, smem + base + dstB + j * 4096);  // rs=0
    }
    asm volatile("s_waitcnt vmcnt(6)" ::: "memory");   // tile0 resident
    __builtin_amdgcn_s_barrier();

    int bufb = 0, sbufb = 2 * TILE_LDS;
    for (int t = 0; t < NT; ++t) {
        const char* base = smem + bufb;
        const bool pf = (t + 2 < NT);
        // ---- phase A: stage A-half of t+2, read frags, 16 MFMA (ti 0-3) ----
        if (pf) {
            const int k0n = (t + 2) * 32;
            #pragma unroll
            for (int j = 0; j < 4; ++j)
                gld16(Wt + aSrc0 + j * (64 * KDIM) + k0n, smem + sbufb + dstA + j * 4096);
        }
        bf16x8 a[8], b[4];
        #pragma unroll
        for (int i = 0; i < 4; ++i) a[i] = *(const bf16x8*)(base + aOff0 + i * 1024);
        #pragma unroll
        for (int j = 0; j < 4; ++j) b[j] = *(const bf16x8*)(base + bOff0 + j * 1024);
        __builtin_amdgcn_s_setprio(1);
        #pragma unroll
        for (int ti = 0; ti < 4; ++ti)
            #pragma unroll
            for (int tj = 0; tj < 4; ++tj)
                acc[ti][tj] = __builtin_amdgcn_mfma_f32_16x16x32_bf16(
                    a[ti], b[tj], acc[ti][tj], 0, 0, 0);
        __builtin_amdgcn_s_setprio(0);
        // ---- phase B: stage B-half of t+2, read frags, 16 MFMA (ti 4-7) ----
        if (pf) {
            const int tt = t + 2;
            const int rs = tt >> 3, c0n = (tt & 7) * 32;
            const int rf = rs / 3, sf = rs - rf * 3;
            const int offxn = (rf * HP + sf) * C_IN + c0n;
            #pragma unroll
            for (int j = 0; j < 2; ++j)
                gld16(xpad + bSrc[j] + offxn, smem + sbufb + dstB + j * 4096);
        }
        #pragma unroll
        for (int i = 4; i < 8; ++i) a[i] = *(const bf16x8*)(base + aOff0 + i * 1024);
        __builtin_amdgcn_s_setprio(1);
        #pragma unroll
        for (int ti = 4; ti < 8; ++ti)
            #pragma unroll
            for (int tj = 0; tj < 4; ++tj)
                acc[ti][tj] = __builtin_amdgcn_mfma_f32_16x16x32_bf16(
                    a[ti], b[tj], acc[ti][tj], 0, 0, 0);
        __builtin_amdgcn_s_setprio(0);
        // ---- tile boundary: counted wait while prefetching, full drain at tail ----
        if (pf)
            asm volatile("s_waitcnt vmcnt(6)" ::: "memory");
        else
            asm volatile("s_waitcnt vmcnt(0)" ::: "memory");
        __builtin_amdgcn_s_barrier();
        bufb += TILE_LDS;  if (bufb == LDS_TOT)  bufb = 0;
        sbufb += TILE_LDS; if (sbufb == LDS_TOT) sbufb = 0;
    }

    // ---- epilogue: C/D layout col=lane&15 (spatial), row=lq*4+r2 (out-ch) ----
    int obase[4];
    #pragma unroll
    for (int tj = 0; tj < 4; ++tj) {
        int p = p0 + wn * 64 + tj * 16 + lm;
        int n = p / 3136; int rem = p - n * 3136;
        obase[tj] = n * (K_OUT * 3136) + rem;
    }
    const int kb = wm * 128 + lq * 4;
    #pragma unroll
    for (int ti = 0; ti < 8; ++ti)
        #pragma unroll
        for (int tj = 0; tj < 4; ++tj) {
            float* op = out + obase[tj] + (kb + ti * 16) * 3136;
            #pragma unroll
            for (int r2 = 0; r2 < 4; ++r2)
                op[r2 * 3136] = acc[ti][tj][r2];
        }
}

// ---------------- fallback (only if ws too small): naive fp32 direct conv ----------------
__global__ void conv_naive(const float* __restrict__ x, const float* __restrict__ W,
                           float* __restrict__ out, int total) {
    int idx = blockIdx.x * 256 + threadIdx.x;
    if (idx >= total) return;
    int n = idx / (K_OUT * 3136); int rem = idx - n * (K_OUT * 3136);
    int k = rem / 3136; rem -= k * 3136;
    int h = rem / 56; int w = rem - h * 56;
    float acc = 0.f;
    for (int c = 0; c < C_IN; ++c) {
        const float* xp = x + ((n * C_IN + c) * HW) * HW;
        const float* wp = W + (k * C_IN + c) * 9;
        #pragma unroll
        for (int r = 0; r < 3; ++r) {
            int hh = h + r - 1;
            if ((unsigned)hh >= HW) continue;
            #pragma unroll
            for (int s = 0; s < 3; ++s) {
                int ww = w + s - 1;
                if ((unsigned)ww >= HW) continue;
                acc += xp[hh * HW + ww] * wp[r * 3 + s];
            }
        }
    }
    out[idx] = acc;
}

extern "C" void kernel_launch(void* const* d_in, const int* in_sizes, int n_in,
                              void* d_out, int out_size, void* d_ws, size_t ws_size,
                              hipStream_t stream) {
    const float* x = (const float*)d_in[0];
    const float* W = (const float*)d_in[1];
    float* out = (float*)d_out;
    const size_t need = (size_t)XPAD_BYTES + WT_BYTES;
    if (ws_size >= need) {
        unsigned short* xpad = (unsigned short*)d_ws;
        unsigned short* Wt = (unsigned short*)((char*)d_ws + XPAD_BYTES);
        prep<<<PREP_BLOCKS, 256, 0, stream>>>(x, W, xpad, Wt);
        conv_gemm<<<SPATIAL / 128, 256, 0, stream>>>(xpad, Wt, out);
    } else {
        conv_naive<<<(OUT_ELEMS + 255) / 256, 256, 0, stream>>>(x, W, out, OUT_ELEMS);
    }
}

// Round 3
// 309.851 us; speedup vs baseline: 1.0334x; 1.0334x over previous
//
#include <hip/hip_runtime.h>
#include <stdint.h>

#define N_IMG 32
#define C_IN 256
#define K_OUT 256
#define HW 56
#define HP 58
#define SPATIAL (N_IMG*HW*HW)          /* 100352 */
#define KDIM (C_IN*9)                  /* 2304 */
#define XPAD_ELEMS (N_IMG*HP*HP*C_IN)  /* 27557888 */
#define XPAD_BYTES (XPAD_ELEMS*2)      /* 55115776 */
#define WT_BYTES (K_OUT*KDIM*2)        /* 1179648 */
#define OUT_ELEMS (N_IMG*K_OUT*HW*HW)  /* 25690112 */

/* GEMM: BM=BN=256, BK=64, 8 waves, 8-phase-style 4-phase/K-tile, 128KB LDS */
#define NT 36                          /* 2304/64 K-tiles */
#define SLOT 65536                     /* A 32K + B 32K per K-tile buffer */
#define GRID_GEMM 392                  /* SPATIAL/256 = 8 XCD x 49 */

/* prep grid partition */
#define PREP_X_BLOCKS (SPATIAL/64)          /* 1568 */
#define PREP_Z_BLOCKS ((N_IMG*228*32)/256)  /* 912 */
#define PREP_W_BLOCKS K_OUT                 /* 256 */
#define PREP_BLOCKS (PREP_X_BLOCKS+PREP_Z_BLOCKS+PREP_W_BLOCKS)

typedef __bf16 bf16x8 __attribute__((ext_vector_type(8)));
typedef float  f32x4  __attribute__((ext_vector_type(4)));

static __device__ __forceinline__ unsigned short f2bf(float f) {
    unsigned u = __float_as_uint(f);
    u += 0x7fff + ((u >> 16) & 1);   // RNE
    return (unsigned short)(u >> 16);
}

static __device__ __forceinline__ void gld16(const void* g, void* l) {
    __builtin_amdgcn_global_load_lds(
        (const __attribute__((address_space(1))) void*)g,
        (__attribute__((address_space(3))) void*)l, 16, 0, 0);
}

// ---------------- fused prep: x->NHWC bf16 padded, border zero, W transform ----
__global__ __launch_bounds__(256) void prep(
    const float* __restrict__ x, const float* __restrict__ W,
    unsigned short* __restrict__ xpad, unsigned short* __restrict__ Wt) {
    const int b = blockIdx.x, t = threadIdx.x;
    if (b < PREP_X_BLOCKS) {
        __shared__ __align__(16) unsigned short lds[64 * 256];   // 32 KB
        const int n = b / 49, hw0 = (b % 49) * 64;
        const int l = t & 63, w0 = t >> 6;
        const float* xbase = x + (size_t)(n * C_IN) * 3136 + hw0 + l;
        #pragma unroll
        for (int i = 0; i < 16; ++i) {
            const int c4 = w0 * 64 + i * 4;      // 4 consecutive channels
            unsigned short v[4];
            #pragma unroll
            for (int j = 0; j < 4; ++j)
                v[j] = f2bf(xbase[(c4 + j) * 3136]);
            const int m = c4 >> 3, h8 = (c4 >> 2) & 1;   // wave-uniform
            *(uint2*)&lds[l * 256 + ((m ^ (l & 31)) << 3) + h8 * 4] = *(const uint2*)v;
        }
        __syncthreads();
        const int q = t & 31;
        #pragma unroll
        for (int j = 0; j < 8; ++j) {
            const int p = (t >> 5) + j * 8;
            const int hw = hw0 + p, h = hw / 56, w = hw - h * 56;
            uint4 v = *(const uint4*)&lds[p * 256 + ((q ^ (p & 31)) << 3)];
            *(uint4*)&xpad[((n * HP + h + 1) * HP + (w + 1)) * C_IN + q * 8] = v;
        }
    } else if (b < PREP_X_BLOCKS + PREP_Z_BLOCKS) {
        // ---- zero the pad border (one uint4 per thread) ----
        int idx = (b - PREP_X_BLOCKS) * 256 + t;
        int cell = idx >> 5, qq = idx & 31;
        int n = cell / 228, r = cell - n * 228;
        int h, w;
        if (r < 58)       { h = 0;            w = r; }
        else if (r < 116) { h = 57;           w = r - 58; }
        else if (r < 172) { h = r - 116 + 1;  w = 0; }
        else              { h = r - 172 + 1;  w = 57; }
        uint4 z = make_uint4(0u, 0u, 0u, 0u);
        *(uint4*)&xpad[((n * HP + h) * HP + w) * C_IN + qq * 8] = z;
    } else {
        // ---- W fp32 OIHW -> bf16 [k][rs][c] ----
        const int k = b - PREP_X_BLOCKS - PREP_Z_BLOCKS, c = t;
        const float* wp = W + (k * C_IN + c) * 9;
        #pragma unroll
        for (int rs = 0; rs < 9; ++rs)
            Wt[k * KDIM + rs * C_IN + c] = f2bf(wp[rs]);
    }
}

// ---------------- main: implicit GEMM, m201-style 8-phase/counted-vmcnt -------
// BM=256 out-ch x BN=256 spatial, BK=64, 512 thr = 8 waves (2M x 4N), per-wave
// 128x64 (acc[8][4]). LDS: 2 slots x 64KB {A[256][64] rows 128B, B likewise}.
// Chunk swizzle (8 chunks/row): phys = logical ^ (row&7) -> uniform bank floor
// on ds_read_b128; staging pre-swizzles the GLOBAL source (linear LDS dest).
// Half-tile ledger (derived from m201's constants, re-verified here):
//   halves per tile: A0(rows 0-127), A1, B0, B1 -- 2 gld16/thread each.
//   entry invariant tile t: t fully resident; {B0,B1,A0}(t+1) in flight (6).
//   ph0: read a[0..3]x2k + b[0..1]x2k, MFMA q0 (ti0-3,tj0-1)
//   ph1: read b[2..3]x2k, stage A1(t+1)->other slot, q1 (ti0-3,tj2-3)
//   ph2: read a[4..7]x2k, stage B0(t+2)->this slot (B0(t) consumed ph0-1), q2
//   ph3: stage B1(t+2)+A0(t+2) (consumed by ph1/ph2), vmcnt(6) [drains ALL of
//        t+1; leaves {B0,B1,A0}(t+2)], q3.  Tail: vmcnt(0) once t+2 >= NT.
// Raw asm s_barrier (memory clobber) -- no compiler vmcnt(0) drain. T5 setprio
// around each MFMA quadrant. Grid 392 = 8 XCDs x 49, bijective swizzle.
__global__ __launch_bounds__(512, 2) void conv_gemm(
    const unsigned short* __restrict__ xpad,
    const unsigned short* __restrict__ Wt,
    float* __restrict__ out) {
    extern __shared__ __align__(16) char smem[];   // 131072 bytes dynamic
    const int tau = threadIdx.x;
    const int w0 = tau >> 6, l = tau & 63;
    const int wm = w0 >> 2, wn = w0 & 3;
    const int lm = l & 15, lq = l >> 4;
    const int bx = blockIdx.x;
    const int p0 = ((bx & 7) * 49 + (bx >> 3)) * 256;   // XCD-swizzled tile base

    // ---- staging geometry: issue = 64 rows x 8 chunks; thread -> row tau>>3,
    // phys chunk tau&7, fetches logical chunk (tau&7)^((tau>>3)&7) ----
    const int sr = tau >> 3;
    const int lc = (tau & 7) ^ (sr & 7);
    int aSrc[4];                      // A issue ja: rows 64*ja + sr
    #pragma unroll
    for (int ja = 0; ja < 4; ++ja)
        aSrc[ja] = (ja * 64 + sr) * KDIM + lc * 8;
    int bSrc[4];                      // B issue jb: spatial p0 + 64*jb + sr
    #pragma unroll
    for (int jb = 0; jb < 4; ++jb) {
        int p = p0 + jb * 64 + sr;
        int n = p / 3136; int rem = p - n * 3136;
        int h = rem / 56; int ww = rem - h * 56;
        bSrc[jb] = ((n * HP + h) * HP + ww) * C_IN + lc * 8;  // r=s=0 base
    }
    const int dstOff = tau * 16;      // sr*128 + (tau&7)*16 == tau*16

    // ---- fragment LDS byte offsets ----
    int aRowB[8], bRowB[4];
    #pragma unroll
    for (int i = 0; i < 8; ++i) aRowB[i] = (wm * 128 + i * 16 + lm) * 128;
    #pragma unroll
    for (int j = 0; j < 4; ++j) bRowB[j] = 32768 + (wn * 64 + j * 16 + lm) * 128;
    const int ch0 = ((0 + lq) ^ (lm & 7)) * 16;   // kk=0 chunk
    const int ch1 = ((4 + lq) ^ (lm & 7)) * 16;   // kk=1 chunk

    f32x4 acc[8][4] = {};

#define STAGE_A(slotb, ja, kofs) \
    gld16(Wt + aSrc[ja] + (kofs), smem + (slotb) + (ja) * 8192 + dstOff)
#define STAGE_B(slotb, jb, ofx) \
    gld16(xpad + bSrc[jb] + (ofx), smem + (slotb) + 32768 + (jb) * 8192 + dstOff)
#define OFFX(tt) (((((tt) >> 2) / 3) * HP + (((tt) >> 2) % 3)) * C_IN + ((tt) & 3) * 64)
#define MFMA1(cc, av, bv) cc = __builtin_amdgcn_mfma_f32_16x16x32_bf16(av, bv, cc, 0, 0, 0)
#define BAR() asm volatile("s_barrier" ::: "memory")

    // ---- prologue: tile0 full (8), then B0,B1,A0 of tile1 (6) ----
    {
        const int ofx0 = OFFX(0), ofx1 = OFFX(1);
        #pragma unroll
        for (int ja = 0; ja < 4; ++ja) STAGE_A(0, ja, 0);
        #pragma unroll
        for (int jb = 0; jb < 4; ++jb) STAGE_B(0, jb, ofx0);
        #pragma unroll
        for (int jb = 0; jb < 4; ++jb) STAGE_B(SLOT, jb, ofx1);   // B0(1),B1(1)
        STAGE_A(SLOT, 0, 64); STAGE_A(SLOT, 1, 64);               // A0(1)
        asm volatile("s_waitcnt vmcnt(6)" ::: "memory");          // tile0 resident
        BAR();
    }

    for (int t = 0; t < NT; ++t) {
        const int sb = (t & 1) * SLOT, osb = sb ^ SLOT;
        const bool pf1 = (t + 1 < NT), pf2 = (t + 2 < NT);
        const int kA1 = (t + 1) * 64, kA2 = (t + 2) * 64;
        const int ofx2 = OFFX(t + 2);
        const char* base = smem + sb;
        bf16x8 aF[4][2], bF[4][2];

        // ---- ph0: a[0..3], b[0..1]; MFMA q0 ----
        #pragma unroll
        for (int i = 0; i < 4; ++i) {
            aF[i][0] = *(const bf16x8*)(base + aRowB[i] + ch0);
            aF[i][1] = *(const bf16x8*)(base + aRowB[i] + ch1);
        }
        #pragma unroll
        for (int j = 0; j < 2; ++j) {
            bF[j][0] = *(const bf16x8*)(base + bRowB[j] + ch0);
            bF[j][1] = *(const bf16x8*)(base + bRowB[j] + ch1);
        }
        BAR();
        __builtin_amdgcn_s_setprio(1);
        #pragma unroll
        for (int i = 0; i < 4; ++i)
            #pragma unroll
            for (int j = 0; j < 2; ++j) {
                MFMA1(acc[i][j], aF[i][0], bF[j][0]);
                MFMA1(acc[i][j], aF[i][1], bF[j][1]);
            }
        __builtin_amdgcn_s_setprio(0);
        BAR();

        // ---- ph1: b[2..3]; stage A1(t+1) -> other slot; MFMA q1 ----
        #pragma unroll
        for (int j = 2; j < 4; ++j) {
            bF[j][0] = *(const bf16x8*)(base + bRowB[j] + ch0);
            bF[j][1] = *(const bf16x8*)(base + bRowB[j] + ch1);
        }
        if (pf1) { STAGE_A(osb, 2, kA1); STAGE_A(osb, 3, kA1); }
        BAR();
        __builtin_amdgcn_s_setprio(1);
        #pragma unroll
        for (int i = 0; i < 4; ++i)
            #pragma unroll
            for (int j = 2; j < 4; ++j) {
                MFMA1(acc[i][j], aF[i][0], bF[j][0]);
                MFMA1(acc[i][j], aF[i][1], bF[j][1]);
            }
        __builtin_amdgcn_s_setprio(0);
        BAR();

        // ---- ph2: a[4..7]; stage B0(t+2) -> this slot; MFMA q2 ----
        #pragma unroll
        for (int i = 0; i < 4; ++i) {
            aF[i][0] = *(const bf16x8*)(base + aRowB[i + 4] + ch0);
            aF[i][1] = *(const bf16x8*)(base + aRowB[i + 4] + ch1);
        }
        if (pf2) { STAGE_B(sb, 0, ofx2); STAGE_B(sb, 1, ofx2); }
        BAR();
        __builtin_amdgcn_s_setprio(1);
        #pragma unroll
        for (int i = 0; i < 4; ++i)
            #pragma unroll
            for (int j = 0; j < 2; ++j) {
                MFMA1(acc[i + 4][j], aF[i][0], bF[j][0]);
                MFMA1(acc[i + 4][j], aF[i][1], bF[j][1]);
            }
        __builtin_amdgcn_s_setprio(0);
        BAR();

        // ---- ph3: stage B1(t+2)+A0(t+2); counted wait; MFMA q3 ----
        if (pf2) {
            STAGE_B(sb, 2, ofx2); STAGE_B(sb, 3, ofx2);
            STAGE_A(sb, 0, kA2);  STAGE_A(sb, 1, kA2);
            asm volatile("s_waitcnt vmcnt(6)" ::: "memory");  // t+1 resident
        } else {
            asm volatile("s_waitcnt vmcnt(0)" ::: "memory");  // tail drain
        }
        BAR();
        __builtin_amdgcn_s_setprio(1);
        #pragma unroll
        for (int i = 0; i < 4; ++i)
            #pragma unroll
            for (int j = 2; j < 4; ++j) {
                MFMA1(acc[i + 4][j], aF[i][0], bF[j][0]);
                MFMA1(acc[i + 4][j], aF[i][1], bF[j][1]);
            }
        __builtin_amdgcn_s_setprio(0);
        BAR();
    }

    // ---- epilogue: C/D col=lane&15 (spatial), row=lq*4+r2 (out-ch) ----
    int obase[4];
    #pragma unroll
    for (int tj = 0; tj < 4; ++tj) {
        int p = p0 + wn * 64 + tj * 16 + lm;
        int n = p / 3136; int rem = p - n * 3136;
        obase[tj] = n * (K_OUT * 3136) + rem;
    }
    const int kb = wm * 128 + lq * 4;
    #pragma unroll
    for (int ti = 0; ti < 8; ++ti)
        #pragma unroll
        for (int tj = 0; tj < 4; ++tj) {
            float* op = out + obase[tj] + (kb + ti * 16) * 3136;
            #pragma unroll
            for (int r2 = 0; r2 < 4; ++r2)
                op[r2 * 3136] = acc[ti][tj][r2];
        }
#undef STAGE_A
#undef STAGE_B
#undef OFFX
#undef MFMA1
#undef BAR
}

// ---------------- fallback (only if ws too small): naive fp32 direct conv ----------------
__global__ void conv_naive(const float* __restrict__ x, const float* __restrict__ W,
                           float* __restrict__ out, int total) {
    int idx = blockIdx.x * 256 + threadIdx.x;
    if (idx >= total) return;
    int n = idx / (K_OUT * 3136); int rem = idx - n * (K_OUT * 3136);
    int k = rem / 3136; rem -= k * 3136;
    int h = rem / 56; int w = rem - h * 56;
    float acc = 0.f;
    for (int c = 0; c < C_IN; ++c) {
        const float* xp = x + ((n * C_IN + c) * HW) * HW;
        const float* wp = W + (k * C_IN + c) * 9;
        #pragma unroll
        for (int r = 0; r < 3; ++r) {
            int hh = h + r - 1;
            if ((unsigned)hh >= HW) continue;
            #pragma unroll
            for (int s = 0; s < 3; ++s) {
                int ww = w + s - 1;
                if ((unsigned)ww >= HW) continue;
                acc += xp[hh * HW + ww] * wp[r * 3 + s];
            }
        }
    }
    out[idx] = acc;
}

extern "C" void kernel_launch(void* const* d_in, const int* in_sizes, int n_in,
                              void* d_out, int out_size, void* d_ws, size_t ws_size,
                              hipStream_t stream) {
    const float* x = (const float*)d_in[0];
    const float* W = (const float*)d_in[1];
    float* out = (float*)d_out;
    const size_t need = (size_t)XPAD_BYTES + WT_BYTES;
    if (ws_size >= need) {
        static bool attr_done = false;
        if (!attr_done) {
            hipFuncSetAttribute((const void*)conv_gemm,
                                hipFuncAttributeMaxDynamicSharedMemorySize, 131072);
            attr_done = true;
        }
        unsigned short* xpad = (unsigned short*)d_ws;
        unsigned short* Wt = (unsigned short*)((char*)d_ws + XPAD_BYTES);
        prep<<<PREP_BLOCKS, 256, 0, stream>>>(x, W, xpad, Wt);
        conv_gemm<<<GRID_GEMM, 512, 131072, stream>>>(xpad, Wt, out);
    } else {
        conv_naive<<<(OUT_ELEMS + 255) / 256, 256, 0, stream>>>(x, W, out, OUT_ELEMS);
    }
}

// Round 4
// 287.712 us; speedup vs baseline: 1.1129x; 1.0769x over previous
//
#include <hip/hip_runtime.h>
#include <stdint.h>

#define N_IMG 32
#define C_IN 256
#define K_OUT 256
#define HW 56
#define HP 58
#define SPATIAL (N_IMG*HW*HW)          /* 100352 */
#define KDIM (C_IN*9)                  /* 2304 */
#define XPAD_ELEMS (N_IMG*HP*HP*C_IN)  /* 27557888 */
#define XPAD_BYTES (XPAD_ELEMS*2)      /* 55115776 */
#define WT_BYTES (K_OUT*KDIM*2)        /* 1179648 */
#define OUT_ELEMS (N_IMG*K_OUT*HW*HW)  /* 25690112 */

/* GEMM: BM=256 out-ch x BN=256 spatial, tap-structured K, 512 thr, grid 392 */
#define GRID_GEMM 392
#define ABUF 16384                 /* A slice: 256 rows x 32ch x 2B */
#define BBUF 49152                 /* B super: 12 rowslots x 64 cols x 32ch x 2B */
#define BBASE (3*ABUF)             /* 49152 */
#define LDS_TOT (3*ABUF + 2*BBUF)  /* 147456 */

/* prep grid partition */
#define PREP_X_BLOCKS (SPATIAL/64)          /* 1568 */
#define PREP_Z_BLOCKS ((N_IMG*228*32)/256)  /* 912 */
#define PREP_W_BLOCKS K_OUT                 /* 256 */
#define PREP_BLOCKS (PREP_X_BLOCKS+PREP_Z_BLOCKS+PREP_W_BLOCKS)

typedef __bf16 bf16x8 __attribute__((ext_vector_type(8)));
typedef float  f32x4  __attribute__((ext_vector_type(4)));

static __device__ __forceinline__ unsigned short f2bf(float f) {
    unsigned u = __float_as_uint(f);
    u += 0x7fff + ((u >> 16) & 1);   // RNE
    return (unsigned short)(u >> 16);
}

static __device__ __forceinline__ void gld16(const void* g, void* l) {
    __builtin_amdgcn_global_load_lds(
        (const __attribute__((address_space(1))) void*)g,
        (__attribute__((address_space(3))) void*)l, 16, 0, 0);
}

// ---------------- fused prep: x->NHWC bf16 padded, border zero, W transform ----
__global__ __launch_bounds__(256) void prep(
    const float* __restrict__ x, const float* __restrict__ W,
    unsigned short* __restrict__ xpad, unsigned short* __restrict__ Wt) {
    const int b = blockIdx.x, t = threadIdx.x;
    if (b < PREP_X_BLOCKS) {
        __shared__ __align__(16) unsigned short lds[64 * 256];   // 32 KB
        const int n = b / 49, hw0 = (b % 49) * 64;
        const int l = t & 63, w0 = t >> 6;
        const float* xbase = x + (size_t)(n * C_IN) * 3136 + hw0 + l;
        #pragma unroll
        for (int i = 0; i < 16; ++i) {
            const int c4 = w0 * 64 + i * 4;      // 4 consecutive channels
            unsigned short v[4];
            #pragma unroll
            for (int j = 0; j < 4; ++j)
                v[j] = f2bf(xbase[(c4 + j) * 3136]);
            const int m = c4 >> 3, h8 = (c4 >> 2) & 1;   // wave-uniform
            *(uint2*)&lds[l * 256 + ((m ^ (l & 31)) << 3) + h8 * 4] = *(const uint2*)v;
        }
        __syncthreads();
        const int q = t & 31;
        #pragma unroll
        for (int j = 0; j < 8; ++j) {
            const int p = (t >> 5) + j * 8;
            const int hw = hw0 + p, h = hw / 56, w = hw - h * 56;
            uint4 v = *(const uint4*)&lds[p * 256 + ((q ^ (p & 31)) << 3)];
            *(uint4*)&xpad[((n * HP + h + 1) * HP + (w + 1)) * C_IN + q * 8] = v;
        }
    } else if (b < PREP_X_BLOCKS + PREP_Z_BLOCKS) {
        // ---- zero the pad border (one uint4 per thread) ----
        int idx = (b - PREP_X_BLOCKS) * 256 + t;
        int cell = idx >> 5, qq = idx & 31;
        int n = cell / 228, r = cell - n * 228;
        int h, w;
        if (r < 58)       { h = 0;            w = r; }
        else if (r < 116) { h = 57;           w = r - 58; }
        else if (r < 172) { h = r - 116 + 1;  w = 0; }
        else              { h = r - 172 + 1;  w = 57; }
        uint4 z = make_uint4(0u, 0u, 0u, 0u);
        *(uint4*)&xpad[((n * HP + h) * HP + w) * C_IN + qq * 8] = z;
    } else {
        // ---- W fp32 OIHW -> bf16 [k][rs][c] ----
        const int k = b - PREP_X_BLOCKS - PREP_Z_BLOCKS, c = t;
        const float* wp = W + (k * C_IN + c) * 9;
        #pragma unroll
        for (int rs = 0; rs < 9; ++rs)
            Wt[k * KDIM + rs * C_IN + c] = f2bf(wp[rs]);
    }
}

// ---------------- main: implicit GEMM with tap-reuse B super-tile -------------
// K restructured as: chunk c (8 x 32 channels) outer, tap t = (r,s) inner (9).
// Per chunk: B super-tile = all xpad ROWS the block touches (<=12 slots, incl.
// +2 tap halo; rows stay within one image since padded rows 0..57 cover h+r),
// 64 cols x 32ch, staged ONCE (48KB) and reused by all 9 taps -> B staging
// traffic drops 3x and becomes contiguous row streams (L2-friendly) instead of
// 9x re-gathered 128B pieces. A (Wt) slice 256x32ch (16KB) per tap, 3-buffer,
// issued 2 taps ahead. One barrier per tap; all waits BEFORE the barrier so it
// certifies block-wide LDS residency (per-wave vmcnt alone can't). Counted
// vmcnt (never 0 mid-loop): per-tap outstanding ledger N' = b[t-1]+2+b[t]
// where b[t]=1 for t<6 (B-super spread over taps 0..5) -> {3,4,4,4,4,4,3,2,2}.
// Tail taps stage wrapped (harmless, valid addresses) so the ledger is uniform.
// LDS chunk swizzle both-sides (rule 21): phys_ch = log_ch ^ ((row_or_col>>1)&3)
// -> 2-way bank aliasing (free, m136) on all ds_read_b128.
__global__ __launch_bounds__(512, 2) void conv_gemm(
    const unsigned short* __restrict__ xpad,
    const unsigned short* __restrict__ Wt,
    float* __restrict__ out) {
    extern __shared__ __align__(16) char smem[];   // 147456 bytes dynamic
    const int tau = threadIdx.x;
    const int w0 = tau >> 6, l = tau & 63;
    const int wm = w0 >> 2, wn = w0 & 3;
    const int lm = l & 15, lq = l >> 4;
    const int bx = blockIdx.x;
    const int p0 = ((bx & 7) * 49 + (bx >> 3)) * 256;   // XCD-swizzled tile base

    // ---- block row-list: rows h0..(hE+2) of n0 (+ seg2 of n1 if crossing) ----
    const int n0 = p0 / 3136, rem0 = p0 - n0 * 3136, h0 = rem0 / 56;
    const int pend = p0 + 255;
    const int n1 = pend / 3136, remE = pend - n1 * 3136, hE = remE / 56;
    const int L1 = (n1 != n0) ? (58 - h0) : (hE - h0 + 3);

    // ---- B staging precompute: issue i covers slots {2i, 2i+1}; this thread
    // serves slot 2i+myHalf, col t8>>2, phys chunk t8&3 (fetches swizzled log) --
    const int myHalf = tau >> 8, t8 = tau & 255;
    const int colS = t8 >> 2;
    const int logS = (t8 & 3) ^ ((colS >> 1) & 3);
    const int srcColByte = colS * 512 + logS * 16;
    int rowBaseByte[6];
    #pragma unroll
    for (int i = 0; i < 6; ++i) {
        int slot = i * 2 + myHalf;
        int xr = (slot < L1) ? (n0 * 58 + h0 + slot) : (n1 * 58 + (slot - L1));
        rowBaseByte[i] = xr * 29696;          // row = 58 cols x 256 ch x 2B
    }

    // ---- A staging precompute: issue ia covers rows ia*128 + (tau>>2) ----
    const int logA = (tau & 3) ^ ((tau >> 3) & 3);
    int aSrcE[2];
    #pragma unroll
    for (int ia = 0; ia < 2; ++ia)
        aSrcE[ia] = (ia * 128 + (tau >> 2)) * KDIM + logA * 8;
    const int aDstOff = tau * 16;

    // ---- fragment precompute ----
    const int chA = (lq ^ ((lm >> 1) & 3)) << 4;
    const int aBase = (wm * 128 + lm) * 64 + chA;          // + i2*1024
    int bB[4], wv[4];
    #pragma unroll
    for (int tj = 0; tj < 4; ++tj) {
        int p = p0 + wn * 64 + tj * 16 + lm;
        int n = p / 3136, remp = p - n * 3136;
        int h = remp / 56, w = remp - h * 56;
        int rowIdx0 = (n == n0) ? (h - h0) : (L1 + h);
        bB[tj] = rowIdx0 * 4096 + w * 64;
        wv[tj] = w;
    }

    f32x4 acc[8][4] = {};

#define SA(bufi, rs2, c2) do { \
    gld16(Wt + aSrcE[0] + (rs2) * 256 + (c2) * 32, smem + (bufi) * ABUF + aDstOff); \
    gld16(Wt + aSrcE[1] + (rs2) * 256 + (c2) * 32, smem + (bufi) * ABUF + 8192 + aDstOff); \
} while (0)
#define SB(par, i, cn) \
    gld16((const char*)xpad + rowBaseByte[i] + (cn) * 64 + srcColByte, \
          smem + BBASE + (par) * BBUF + ((i) * 2 + myHalf) * 4096 + t8 * 16)
#define BAR() asm volatile("s_barrier" ::: "memory")

    // ---- prologue: A(0)->buf0, A(1)->buf1, B(chunk0)->par0; full drain ----
    SA(0, 0, 0);
    SA(1, 1, 0);
    #pragma unroll
    for (int i = 0; i < 6; ++i) SB(0, i, 0);
    asm volatile("s_waitcnt vmcnt(0)" ::: "memory");
    BAR();

    for (int c = 0; c < 8; ++c) {
        const char* Bcur = smem + BBASE + (c & 1) * BBUF;
        const int cn1 = (c + 1) & 7, bn = (c + 1) & 1;
        #pragma unroll
        for (int t = 0; t < 9; ++t) {
            // ---- reads (tap t): A from buf t%3, B from super at (r,s) shift --
            const char* Acur = smem + (t % 3) * ABUF;
            bf16x8 a[8], b[4];
            #pragma unroll
            for (int i2 = 0; i2 < 8; ++i2)
                a[i2] = *(const bf16x8*)(Acur + aBase + i2 * 1024);
            const int r = t / 3, s = t - r * 3;
            #pragma unroll
            for (int tj = 0; tj < 4; ++tj) {
                const int cb = wv[tj] + s;
                b[tj] = *(const bf16x8*)(Bcur + bB[tj] + r * 4096 + s * 64
                          + ((lq ^ ((cb >> 1) & 3)) << 4));
            }
            // ---- stage A(t+2) (2 taps ahead, 3-buffer) + B-super share ----
            { const int rs2 = (t + 2) % 9, c2 = (t <= 6) ? c : cn1;
              SA((t + 2) % 3, rs2, c2); }
            if (t < 6) SB(bn, t, cn1);
            // ---- counted wait BEFORE barrier: certifies A(t+1) (+B at wrap) --
            if (t == 7 || t == 8)      asm volatile("s_waitcnt vmcnt(2)" ::: "memory");
            else if (t == 0 || t == 6) asm volatile("s_waitcnt vmcnt(3)" ::: "memory");
            else                       asm volatile("s_waitcnt vmcnt(4)" ::: "memory");
            BAR();
            // ---- 32 MFMA (K=32 tap slice) ----
            __builtin_amdgcn_s_setprio(1);
            #pragma unroll
            for (int i2 = 0; i2 < 8; ++i2)
                #pragma unroll
                for (int tj = 0; tj < 4; ++tj)
                    acc[i2][tj] = __builtin_amdgcn_mfma_f32_16x16x32_bf16(
                        a[i2], b[tj], acc[i2][tj], 0, 0, 0);
            __builtin_amdgcn_s_setprio(0);
        }
    }

    // ---- epilogue: C/D layout col=lane&15 (spatial), row=lq*4+r2 (out-ch) ----
    int obase[4];
    #pragma unroll
    for (int tj = 0; tj < 4; ++tj) {
        int p = p0 + wn * 64 + tj * 16 + lm;
        int n = p / 3136; int rem = p - n * 3136;
        obase[tj] = n * (K_OUT * 3136) + rem;
    }
    const int kb = wm * 128 + lq * 4;
    #pragma unroll
    for (int ti = 0; ti < 8; ++ti)
        #pragma unroll
        for (int tj = 0; tj < 4; ++tj) {
            float* op = out + obase[tj] + (kb + ti * 16) * 3136;
            #pragma unroll
            for (int r2 = 0; r2 < 4; ++r2)
                op[r2 * 3136] = acc[ti][tj][r2];
        }
#undef SA
#undef SB
#undef BAR
}

// ---------------- fallback (only if ws too small): naive fp32 direct conv ----------------
__global__ void conv_naive(const float* __restrict__ x, const float* __restrict__ W,
                           float* __restrict__ out, int total) {
    int idx = blockIdx.x * 256 + threadIdx.x;
    if (idx >= total) return;
    int n = idx / (K_OUT * 3136); int rem = idx - n * (K_OUT * 3136);
    int k = rem / 3136; rem -= k * 3136;
    int h = rem / 56; int w = rem - h * 56;
    float acc = 0.f;
    for (int c = 0; c < C_IN; ++c) {
        const float* xp = x + ((n * C_IN + c) * HW) * HW;
        const float* wp = W + (k * C_IN + c) * 9;
        #pragma unroll
        for (int r = 0; r < 3; ++r) {
            int hh = h + r - 1;
            if ((unsigned)hh >= HW) continue;
            #pragma unroll
            for (int s = 0; s < 3; ++s) {
                int ww = w + s - 1;
                if ((unsigned)ww >= HW) continue;
                acc += xp[hh * HW + ww] * wp[r * 3 + s];
            }
        }
    }
    out[idx] = acc;
}

extern "C" void kernel_launch(void* const* d_in, const int* in_sizes, int n_in,
                              void* d_out, int out_size, void* d_ws, size_t ws_size,
                              hipStream_t stream) {
    const float* x = (const float*)d_in[0];
    const float* W = (const float*)d_in[1];
    float* out = (float*)d_out;
    const size_t need = (size_t)XPAD_BYTES + WT_BYTES;
    if (ws_size >= need) {
        static bool attr_done = false;
        if (!attr_done) {
            hipFuncSetAttribute((const void*)conv_gemm,
                                hipFuncAttributeMaxDynamicSharedMemorySize, LDS_TOT);
            attr_done = true;
        }
        unsigned short* xpad = (unsigned short*)d_ws;
        unsigned short* Wt = (unsigned short*)((char*)d_ws + XPAD_BYTES);
        prep<<<PREP_BLOCKS, 256, 0, stream>>>(x, W, xpad, Wt);
        conv_gemm<<<GRID_GEMM, 512, LDS_TOT, stream>>>(xpad, Wt, out);
    } else {
        conv_naive<<<(OUT_ELEMS + 255) / 256, 256, 0, stream>>>(x, W, out, OUT_ELEMS);
    }
}